// Round 1
// baseline (3485.249 us; speedup 1.0000x reference)
//
#include <hip/hip_runtime.h>
#include <math.h>

#define H 256
#define G3 768        // 3*H
#define BB 512
#define AA 4
#define EE 10
#define RP (BB*AA*EE) // 20480 physical rows
#define RA (BB*AA)    // 2048 action rows
#define TT 10
#define NMV 2
#define STEPSC 0.05f

__device__ __forceinline__ float sigmoid_(float x){ return 1.f/(1.f + __expf(-x)); }
__device__ __forceinline__ float tanh_(float x){
    float ax = fabsf(x);
    float e  = __expf(-2.f*ax);
    float t  = (1.f - e)/(1.f + e);
    return copysignf(t, x);
}
__device__ __forceinline__ float elu_(float x){ return x > 0.f ? x : (__expf(x) - 1.f); }

// ---------------------------------------------------------------------------
// gia_goal[ra][k] = b_ih_a[k] + sum_{j<3} goals[ra][j] * W_ih_a[k][256+j]
// (time-invariant part of the action GRU input gates)
// ---------------------------------------------------------------------------
__global__ void k_gia_goal(const float* __restrict__ goals,
                           const float* __restrict__ Wiha,
                           const float* __restrict__ biha,
                           float* __restrict__ out)
{
    int idx = blockIdx.x*256 + threadIdx.x;   // RA*G3 total
    int ra = idx / G3, k = idx % G3;
    float g0 = goals[ra*3+0], g1 = goals[ra*3+1], g2 = goals[ra*3+2];
    const float* w = Wiha + (size_t)k*259 + 256;
    out[idx] = biha[k] + g0*w[0] + g1*w[1] + g2*w[2];
}

// ---------------------------------------------------------------------------
// Fused GRU step: gh = h_in @ Whh^T (tiled GEMM) + gate math -> h_out
// Block: 256 thr, tile 64 rows x 64 cols (of the 256 h-cols), grid.y = 4 chunks.
// Each thread: 4x4 outputs x 3 gates = 48 accumulators.
// INLINE_GI=1: recompute input gates from x_p = cat(obs, phys) (K=5, cheap).
// INLINE_GI=0: read precomputed gi buffer [rows][768].
// ---------------------------------------------------------------------------
template<int INLINE_GI>
__global__ __launch_bounds__(256)
void k_gru(const float* __restrict__ h_in, float* __restrict__ h_out,
           const float* __restrict__ gi,
           const float* __restrict__ obs, const float* __restrict__ phys,
           const float* __restrict__ Wih, const float* __restrict__ bih,
           const float* __restrict__ Whh, const float* __restrict__ bhh)
{
    __shared__ float Xs[32][64];    // [kk][m]  transposed h tile slice
    __shared__ float Ws[32][192];   // [kk][gate*64 + c] weight slice (3 gates)

    const int m0 = blockIdx.x * 64;
    const int j0 = blockIdx.y * 64;
    const int tid = threadIdx.x;
    const int tr = tid & 15, tc = tid >> 4;

    float acc[3][16];
    #pragma unroll
    for (int g = 0; g < 3; g++)
        #pragma unroll
        for (int i = 0; i < 16; i++) acc[g][i] = 0.f;

    for (int k0 = 0; k0 < H; k0 += 32) {
        // stage X (64 rows x 32 k): float4 along k, store transposed
        #pragma unroll
        for (int i = 0; i < 2; i++) {
            int f = tid + 256*i;
            int m = f & 63, kk = (f >> 6) << 2;
            float4 v = *(const float4*)(h_in + (size_t)(m0+m)*H + k0 + kk);
            Xs[kk+0][m]=v.x; Xs[kk+1][m]=v.y; Xs[kk+2][m]=v.z; Xs[kk+3][m]=v.w;
        }
        // stage W (192 rows x 32 k): rows = 3 gates x 64 cols of this chunk
        #pragma unroll
        for (int i = 0; i < 6; i++) {
            int f = tid + 256*i;
            int c = f % 192, kk = (f / 192) << 2;
            int gate = c / 64, jc = j0 + (c & 63);
            float4 v = *(const float4*)(Whh + (size_t)(gate*H + jc)*H + k0 + kk);
            Ws[kk+0][c]=v.x; Ws[kk+1][c]=v.y; Ws[kk+2][c]=v.z; Ws[kk+3][c]=v.w;
        }
        __syncthreads();
        #pragma unroll
        for (int kk = 0; kk < 32; kk++) {
            float4 a = *(const float4*)&Xs[kk][tr*4];
            float av[4] = {a.x, a.y, a.z, a.w};
            #pragma unroll
            for (int g = 0; g < 3; g++) {
                float4 b = *(const float4*)&Ws[kk][g*64 + tc*4];
                float bv[4] = {b.x, b.y, b.z, b.w};
                #pragma unroll
                for (int ri = 0; ri < 4; ri++)
                    #pragma unroll
                    for (int ci = 0; ci < 4; ci++)
                        acc[g][ri*4+ci] = fmaf(av[ri], bv[ci], acc[g][ri*4+ci]);
            }
        }
        __syncthreads();
    }

    // epilogue: gates + state update
    float xv[4][5];
    if (INLINE_GI) {
        #pragma unroll
        for (int ri = 0; ri < 4; ri++) {
            int row = m0 + tr*4 + ri;
            int b = row / (AA*EE);
            int e = row % EE;
            xv[ri][0] = obs[(size_t)row*2+0];
            xv[ri][1] = obs[(size_t)row*2+1];
            const float* pp = phys + (size_t)(b*EE + e)*3;
            xv[ri][2]=pp[0]; xv[ri][3]=pp[1]; xv[ri][4]=pp[2];
        }
    }
    #pragma unroll
    for (int ri = 0; ri < 4; ri++) {
        int row = m0 + tr*4 + ri;
        #pragma unroll
        for (int ci = 0; ci < 4; ci++) {
            int col = j0 + tc*4 + ci;
            float gr, gz, gn;
            if (INLINE_GI) {
                const float* wr = Wih + (size_t)col*5;
                const float* wz = Wih + (size_t)(256+col)*5;
                const float* wn = Wih + (size_t)(512+col)*5;
                gr = bih[col]; gz = bih[256+col]; gn = bih[512+col];
                #pragma unroll
                for (int j = 0; j < 5; j++) {
                    gr = fmaf(xv[ri][j], wr[j], gr);
                    gz = fmaf(xv[ri][j], wz[j], gz);
                    gn = fmaf(xv[ri][j], wn[j], gn);
                }
            } else {
                const float* gp = gi + (size_t)row*G3;
                gr = gp[col]; gz = gp[256+col]; gn = gp[512+col];
            }
            float hr = acc[0][ri*4+ci] + bhh[col];
            float hz = acc[1][ri*4+ci] + bhh[256+col];
            float hn = acc[2][ri*4+ci] + bhh[512+col];
            float r = sigmoid_(gr + hr);
            float z = sigmoid_(gz + hz);
            float n = tanh_(gn + r*hn);
            float ho = h_in[(size_t)row*H + col];
            h_out[(size_t)row*H + col] = (1.f - z)*n + z*ho;
        }
    }
}

// ---------------------------------------------------------------------------
// Generic C[M x N] = act( X[M x 256] @ W^T (+ bias | + Cin) )
// W rows have leading dim ldw (259 for W_ih_a, else 256). ACT: 0 none, 1 elu.
// ADD: add Cin (bias assumed folded into Cin) instead of bias.
// ---------------------------------------------------------------------------
template<int ACT, int ADD>
__global__ __launch_bounds__(256)
void k_gemm(const float* __restrict__ X, const float* __restrict__ W, int ldw,
            const float* __restrict__ bias, const float* __restrict__ Cin,
            float* __restrict__ C, int N)
{
    __shared__ float Xs[32][64];
    __shared__ float Ws[32][64];
    const int m0 = blockIdx.x*64, n0 = blockIdx.y*64;
    const int tid = threadIdx.x, tr = tid & 15, tc = tid >> 4;
    float acc[16];
    #pragma unroll
    for (int i = 0; i < 16; i++) acc[i] = 0.f;

    for (int k0 = 0; k0 < H; k0 += 32) {
        #pragma unroll
        for (int i = 0; i < 2; i++) {
            int f = tid + 256*i;
            int m = f & 63, kk = (f >> 6) << 2;
            float4 v = *(const float4*)(X + (size_t)(m0+m)*H + k0 + kk);
            Xs[kk+0][m]=v.x; Xs[kk+1][m]=v.y; Xs[kk+2][m]=v.z; Xs[kk+3][m]=v.w;
            // W may have ldw=259 (rows not 16B-aligned) -> scalar loads
            const float* wp = W + (size_t)(n0+m)*ldw + k0 + kk;
            Ws[kk+0][m]=wp[0]; Ws[kk+1][m]=wp[1]; Ws[kk+2][m]=wp[2]; Ws[kk+3][m]=wp[3];
        }
        __syncthreads();
        #pragma unroll
        for (int kk = 0; kk < 32; kk++) {
            float4 a = *(const float4*)&Xs[kk][tr*4];
            float4 b = *(const float4*)&Ws[kk][tc*4];
            float av[4] = {a.x,a.y,a.z,a.w};
            float bv[4] = {b.x,b.y,b.z,b.w};
            #pragma unroll
            for (int ri = 0; ri < 4; ri++)
                #pragma unroll
                for (int ci = 0; ci < 4; ci++)
                    acc[ri*4+ci] = fmaf(av[ri], bv[ci], acc[ri*4+ci]);
        }
        __syncthreads();
    }
    #pragma unroll
    for (int ri = 0; ri < 4; ri++) {
        int row = m0 + tr*4 + ri;
        #pragma unroll
        for (int ci = 0; ci < 4; ci++) {
            int col = n0 + tc*4 + ci;
            float v = acc[ri*4+ci];
            if (ADD) v += Cin[(size_t)row*N + col];
            else     v += bias[col];
            if (ACT == 1) v = elu_(v);
            C[(size_t)row*N + col] = v;
        }
    }
}

// feat[ba][j] = max_e proc[ba*EE + e][j]
__global__ void k_pool(const float* __restrict__ proc, float* __restrict__ feat)
{
    int idx = blockIdx.x*256 + threadIdx.x;   // RA*H
    int ba = idx >> 8, j = idx & 255;
    const float* p = proc + (size_t)ba*EE*H + j;
    float m = p[0];
    #pragma unroll
    for (int e = 1; e < EE; e++) m = fmaxf(m, p[(size_t)e*H]);
    feat[idx] = m;
}

// out[row][v] = tanh(b_m2[v] + m1o[row] . W_m2[v]) * STEP
__global__ void k_m2(const float* __restrict__ X, const float* __restrict__ Wm2,
                     const float* __restrict__ bm2, float* __restrict__ out)
{
    int idx = blockIdx.x*256 + threadIdx.x;   // RA*NMV
    int row = idx >> 1, v = idx & 1;
    const float4* x = (const float4*)(X + (size_t)row*H);
    const float4* w = (const float4*)(Wm2 + (size_t)v*H);
    float s = bm2[v];
    #pragma unroll 4
    for (int i = 0; i < H/4; i++) {
        float4 a = x[i], b = w[i];
        s = fmaf(a.x, b.x, s); s = fmaf(a.y, b.y, s);
        s = fmaf(a.z, b.z, s); s = fmaf(a.w, b.w, s);
    }
    out[idx] = tanh_(s) * STEPSC;
}

extern "C" void kernel_launch(void* const* d_in, const int* in_sizes, int n_in,
                              void* d_out, int out_size, void* d_ws, size_t ws_size,
                              hipStream_t stream)
{
    const float* obs  = (const float*)d_in[0];
    const float* phys = (const float*)d_in[1];
    const float* goals= (const float*)d_in[2];
    const float* memp = (const float*)d_in[3];
    const float* mema = (const float*)d_in[4];
    const float* Wihp = (const float*)d_in[5];
    const float* Whhp = (const float*)d_in[6];
    const float* bihp = (const float*)d_in[7];
    const float* bhhp = (const float*)d_in[8];
    const float* Wfcp = (const float*)d_in[9];
    const float* bfcp = (const float*)d_in[10];
    const float* Wiha = (const float*)d_in[11];
    const float* Whha = (const float*)d_in[12];
    const float* biha = (const float*)d_in[13];
    const float* bhha = (const float*)d_in[14];
    const float* Wfca = (const float*)d_in[15];
    const float* bfca = (const float*)d_in[16];
    const float* Wm1  = (const float*)d_in[17];
    const float* bm1  = (const float*)d_in[18];
    const float* Wm2  = (const float*)d_in[19];
    const float* bm2  = (const float*)d_in[20];
    float* out = (float*)d_out;

    float* ws = (float*)d_ws;
    float* gia_goal = ws; ws += (size_t)RA*G3;
    float* gi_a     = ws; ws += (size_t)RA*G3;
    float* hp0      = ws; ws += (size_t)RP*H;
    float* hp1      = ws; ws += (size_t)RP*H;
    float* ha0      = ws; ws += (size_t)RA*H;
    float* ha1      = ws; ws += (size_t)RA*H;
    float* proc     = ws; ws += (size_t)RP*H;
    float* feat     = ws; ws += (size_t)RA*H;
    float* proca    = ws; ws += (size_t)RA*H;
    float* m1o      = ws; ws += (size_t)RA*H;

    hipMemcpyAsync(hp0, memp, sizeof(float)*(size_t)RP*H, hipMemcpyDeviceToDevice, stream);
    hipMemcpyAsync(ha0, mema, sizeof(float)*(size_t)RA*H, hipMemcpyDeviceToDevice, stream);
    k_gia_goal<<<RA*G3/256, 256, 0, stream>>>(goals, Wiha, biha, gia_goal);

    float* hpi = hp0; float* hpo = hp1;
    float* hai = ha0; float* hao = ha1;
    for (int t = 0; t < TT; t++) {
        // physical chain
        k_gru<1><<<dim3(RP/64, 4), 256, 0, stream>>>(hpi, hpo, nullptr,
                                                     obs, phys, Wihp, bihp, Whhp, bhhp);
        k_gemm<1,0><<<dim3(RP/64, H/64), 256, 0, stream>>>(hpo, Wfcp, H, bfcp, nullptr, proc, H);
        k_pool<<<RA*H/256, 256, 0, stream>>>(proc, feat);
        // action chain
        k_gemm<0,1><<<dim3(RA/64, G3/64), 256, 0, stream>>>(feat, Wiha, 259, nullptr, gia_goal, gi_a, G3);
        k_gru<0><<<dim3(RA/64, 4), 256, 0, stream>>>(hai, hao, gi_a,
                                                     nullptr, nullptr, nullptr, nullptr, Whha, bhha);
        k_gemm<1,0><<<dim3(RA/64, H/64), 256, 0, stream>>>(hao, Wfca, H, bfca, nullptr, proca, H);
        k_gemm<1,0><<<dim3(RA/64, H/64), 256, 0, stream>>>(proca, Wm1, H, bm1, nullptr, m1o, H);
        k_m2<<<RA*NMV/256, 256, 0, stream>>>(m1o, Wm2, bm2, out + (size_t)t*RA*NMV);

        float* tmp = hpi; hpi = hpo; hpo = tmp;
        tmp = hai; hai = hao; hao = tmp;
    }
}

// Round 2
// 2439.605 us; speedup vs baseline: 1.4286x; 1.4286x over previous
//
#include <hip/hip_runtime.h>
#include <math.h>

#define H 256
#define G3 768        // 3*H
#define BB 512
#define AA 4
#define EE 10
#define RP (BB*AA*EE) // 20480 physical rows
#define RA (BB*AA)    // 2048 action rows
#define TT 10
#define NMV 2
#define STEPSC 0.05f

typedef __attribute__((ext_vector_type(8))) short short8;
typedef __attribute__((ext_vector_type(4))) float f32x4;

__device__ __forceinline__ float sigmoid_(float x){ return 1.f/(1.f + __expf(-x)); }
__device__ __forceinline__ float tanh_(float x){
    float ax = fabsf(x);
    float e  = __expf(-2.f*ax);
    float t  = (1.f - e)/(1.f + e);
    return copysignf(t, x);
}
__device__ __forceinline__ float elu_(float x){ return x > 0.f ? x : (__expf(x) - 1.f); }

// bf16 helpers (RNE), stored as raw unsigned short
__device__ __forceinline__ unsigned short f2bf(float x){
    union { float f; unsigned int u; } v; v.f = x;
    unsigned int r = v.u + 0x7fffu + ((v.u >> 16) & 1u);
    return (unsigned short)(r >> 16);
}
__device__ __forceinline__ float bf2f(unsigned short b){
    union { unsigned int u; float f; } v; v.u = ((unsigned int)b) << 16; return v.f;
}

// ---------------------------------------------------------------------------
// split fp32 -> (hi, lo) bf16 pair: hi = bf16(x), lo = bf16(x - hi)
// ---------------------------------------------------------------------------
__global__ void k_split(const float* __restrict__ src,
                        unsigned short* __restrict__ hi,
                        unsigned short* __restrict__ lo, int n)
{
    int i = blockIdx.x*256 + threadIdx.x;
    if (i < n) {
        float x = src[i];
        unsigned short h = f2bf(x);
        hi[i] = h;
        lo[i] = f2bf(x - bf2f(h));
    }
}

// ---------------------------------------------------------------------------
// gia_goal[ra][k] = b_ih_a[k] + sum_{j<3} goals[ra][j] * W_ih_a[k][256+j]
// ---------------------------------------------------------------------------
__global__ void k_gia_goal(const float* __restrict__ goals,
                           const float* __restrict__ Wiha,
                           const float* __restrict__ biha,
                           float* __restrict__ out)
{
    int idx = blockIdx.x*256 + threadIdx.x;   // RA*G3 total
    int ra = idx / G3, k = idx % G3;
    float g0 = goals[ra*3+0], g1 = goals[ra*3+1], g2 = goals[ra*3+2];
    const float* w = Wiha + (size_t)k*259 + 256;
    out[idx] = biha[k] + g0*w[0] + g1*w[1] + g2*w[2];
}

// ---------------------------------------------------------------------------
// Fused MFMA GRU step (physical chain), split-bf16 (hi/lo) x3-MFMA matmul.
// gh = h @ Whh^T via mfma_f32_16x16x32_bf16; gate math in epilogue; h state
// kept as (hi, lo) bf16 pair (reconstruction error ~2^-17).
// Block 256 thr = 4 waves; block tile 128 rows; grid.y*32 = cols; all 3 gates.
// Wave tile: 32 rows x 32 cols x 3 gates -> 12 acc frags (48 VGPR).
// ---------------------------------------------------------------------------
__global__ __launch_bounds__(256)
void k_gru_mfma(const unsigned short* __restrict__ h_hi, const unsigned short* __restrict__ h_lo,
                unsigned short* __restrict__ o_hi, unsigned short* __restrict__ o_lo,
                const unsigned short* __restrict__ w_hi, const unsigned short* __restrict__ w_lo,
                const float* __restrict__ obs, const float* __restrict__ phys,
                const float* __restrict__ Wih, const float* __restrict__ bih,
                const float* __restrict__ bhh)
{
    const int tid  = threadIdx.x;
    const int wv   = tid >> 6;
    const int lane = tid & 63;
    const int quad = lane >> 4, l16 = lane & 15;
    const int m0 = blockIdx.x*128 + wv*32;
    const int j0 = blockIdx.y*32;

    f32x4 acc[3][2][2];   // [gate][mi][ni]
    #pragma unroll
    for (int g = 0; g < 3; g++)
        #pragma unroll
        for (int mi = 0; mi < 2; mi++)
            #pragma unroll
            for (int ni = 0; ni < 2; ni++)
                acc[g][mi][ni] = (f32x4){0.f,0.f,0.f,0.f};

    const size_t aoff0 = (size_t)(m0 + l16)*H + quad*8;
    const size_t aoff1 = aoff0 + (size_t)16*H;
    size_t boff[3][2];
    #pragma unroll
    for (int g = 0; g < 3; g++)
        #pragma unroll
        for (int ni = 0; ni < 2; ni++)
            boff[g][ni] = (size_t)(g*H + j0 + ni*16 + l16)*H + quad*8;

    for (int k0 = 0; k0 < H; k0 += 32) {
        short8 ahi0 = *(const short8*)(h_hi + aoff0 + k0);
        short8 alo0 = *(const short8*)(h_lo + aoff0 + k0);
        short8 ahi1 = *(const short8*)(h_hi + aoff1 + k0);
        short8 alo1 = *(const short8*)(h_lo + aoff1 + k0);
        #pragma unroll
        for (int g = 0; g < 3; g++) {
            #pragma unroll
            for (int ni = 0; ni < 2; ni++) {
                short8 bhi = *(const short8*)(w_hi + boff[g][ni] + k0);
                short8 blo = *(const short8*)(w_lo + boff[g][ni] + k0);
                acc[g][0][ni] = __builtin_amdgcn_mfma_f32_16x16x32_bf16(ahi0, bhi, acc[g][0][ni], 0,0,0);
                acc[g][0][ni] = __builtin_amdgcn_mfma_f32_16x16x32_bf16(alo0, bhi, acc[g][0][ni], 0,0,0);
                acc[g][0][ni] = __builtin_amdgcn_mfma_f32_16x16x32_bf16(ahi0, blo, acc[g][0][ni], 0,0,0);
                acc[g][1][ni] = __builtin_amdgcn_mfma_f32_16x16x32_bf16(ahi1, bhi, acc[g][1][ni], 0,0,0);
                acc[g][1][ni] = __builtin_amdgcn_mfma_f32_16x16x32_bf16(alo1, bhi, acc[g][1][ni], 0,0,0);
                acc[g][1][ni] = __builtin_amdgcn_mfma_f32_16x16x32_bf16(ahi1, blo, acc[g][1][ni], 0,0,0);
            }
        }
    }

    // --- epilogue: inline input gates (K=5) + GRU update + hi/lo store ---
    float wr[2][5], wz[2][5], wn[2][5];
    float br[2], bz[2], bn[2], bhr[2], bhz[2], bhn[2];
    #pragma unroll
    for (int ni = 0; ni < 2; ni++) {
        int col = j0 + ni*16 + l16;
        const float* pr = Wih + (size_t)col*5;
        const float* pz = Wih + (size_t)(256+col)*5;
        const float* pn = Wih + (size_t)(512+col)*5;
        #pragma unroll
        for (int j = 0; j < 5; j++) { wr[ni][j]=pr[j]; wz[ni][j]=pz[j]; wn[ni][j]=pn[j]; }
        br[ni] = bih[col]; bz[ni] = bih[256+col]; bn[ni] = bih[512+col];
        bhr[ni]= bhh[col]; bhz[ni]= bhh[256+col]; bhn[ni]= bhh[512+col];
    }
    #pragma unroll
    for (int mi = 0; mi < 2; mi++) {
        #pragma unroll
        for (int r = 0; r < 4; r++) {
            int row = m0 + mi*16 + quad*4 + r;
            float x0 = obs[(size_t)row*2+0];
            float x1 = obs[(size_t)row*2+1];
            int b = row / (AA*EE);
            int e = row % EE;
            const float* pp = phys + (size_t)(b*EE + e)*3;
            float x2 = pp[0], x3 = pp[1], x4 = pp[2];
            #pragma unroll
            for (int ni = 0; ni < 2; ni++) {
                int col = j0 + ni*16 + l16;
                float gr = br[ni], gz = bz[ni], gn = bn[ni];
                gr = fmaf(x0,wr[ni][0],gr); gr = fmaf(x1,wr[ni][1],gr); gr = fmaf(x2,wr[ni][2],gr);
                gr = fmaf(x3,wr[ni][3],gr); gr = fmaf(x4,wr[ni][4],gr);
                gz = fmaf(x0,wz[ni][0],gz); gz = fmaf(x1,wz[ni][1],gz); gz = fmaf(x2,wz[ni][2],gz);
                gz = fmaf(x3,wz[ni][3],gz); gz = fmaf(x4,wz[ni][4],gz);
                gn = fmaf(x0,wn[ni][0],gn); gn = fmaf(x1,wn[ni][1],gn); gn = fmaf(x2,wn[ni][2],gn);
                gn = fmaf(x3,wn[ni][3],gn); gn = fmaf(x4,wn[ni][4],gn);
                float hr = acc[0][mi][ni][r] + bhr[ni];
                float hz = acc[1][mi][ni][r] + bhz[ni];
                float hn = acc[2][mi][ni][r] + bhn[ni];
                float rg = sigmoid_(gr + hr);
                float z  = sigmoid_(gz + hz);
                float n  = tanh_(gn + rg*hn);
                size_t idx = (size_t)row*H + col;
                float hprev = bf2f(h_hi[idx]) + bf2f(h_lo[idx]);
                float h = (1.f - z)*n + z*hprev;
                unsigned short hb = f2bf(h);
                o_hi[idx] = hb;
                o_lo[idx] = f2bf(h - bf2f(hb));
            }
        }
    }
}

// ---------------------------------------------------------------------------
// MFMA fc: out[M x 256] = elu( h @ W^T + bias ), h/W in split-bf16.
// Wave tile 32 rows x 64 cols. Grid: (M/128, 256/64).
// ---------------------------------------------------------------------------
__global__ __launch_bounds__(256)
void k_fc_mfma(const unsigned short* __restrict__ h_hi, const unsigned short* __restrict__ h_lo,
               const unsigned short* __restrict__ w_hi, const unsigned short* __restrict__ w_lo,
               const float* __restrict__ bias, float* __restrict__ out)
{
    const int tid  = threadIdx.x;
    const int wv   = tid >> 6;
    const int lane = tid & 63;
    const int quad = lane >> 4, l16 = lane & 15;
    const int m0 = blockIdx.x*128 + wv*32;
    const int j0 = blockIdx.y*64;

    f32x4 acc[2][4];
    #pragma unroll
    for (int mi = 0; mi < 2; mi++)
        #pragma unroll
        for (int ni = 0; ni < 4; ni++)
            acc[mi][ni] = (f32x4){0.f,0.f,0.f,0.f};

    const size_t aoff0 = (size_t)(m0 + l16)*H + quad*8;
    const size_t aoff1 = aoff0 + (size_t)16*H;
    size_t boff[4];
    #pragma unroll
    for (int ni = 0; ni < 4; ni++)
        boff[ni] = (size_t)(j0 + ni*16 + l16)*H + quad*8;

    for (int k0 = 0; k0 < H; k0 += 32) {
        short8 ahi0 = *(const short8*)(h_hi + aoff0 + k0);
        short8 alo0 = *(const short8*)(h_lo + aoff0 + k0);
        short8 ahi1 = *(const short8*)(h_hi + aoff1 + k0);
        short8 alo1 = *(const short8*)(h_lo + aoff1 + k0);
        #pragma unroll
        for (int ni = 0; ni < 4; ni++) {
            short8 bhi = *(const short8*)(w_hi + boff[ni] + k0);
            short8 blo = *(const short8*)(w_lo + boff[ni] + k0);
            acc[0][ni] = __builtin_amdgcn_mfma_f32_16x16x32_bf16(ahi0, bhi, acc[0][ni], 0,0,0);
            acc[0][ni] = __builtin_amdgcn_mfma_f32_16x16x32_bf16(alo0, bhi, acc[0][ni], 0,0,0);
            acc[0][ni] = __builtin_amdgcn_mfma_f32_16x16x32_bf16(ahi0, blo, acc[0][ni], 0,0,0);
            acc[1][ni] = __builtin_amdgcn_mfma_f32_16x16x32_bf16(ahi1, bhi, acc[1][ni], 0,0,0);
            acc[1][ni] = __builtin_amdgcn_mfma_f32_16x16x32_bf16(alo1, bhi, acc[1][ni], 0,0,0);
            acc[1][ni] = __builtin_amdgcn_mfma_f32_16x16x32_bf16(ahi1, blo, acc[1][ni], 0,0,0);
        }
    }
    #pragma unroll
    for (int mi = 0; mi < 2; mi++) {
        #pragma unroll
        for (int r = 0; r < 4; r++) {
            int row = m0 + mi*16 + quad*4 + r;
            #pragma unroll
            for (int ni = 0; ni < 4; ni++) {
                int col = j0 + ni*16 + l16;
                float v = acc[mi][ni][r] + bias[col];
                out[(size_t)row*H + col] = elu_(v);
            }
        }
    }
}

// ---------------------------------------------------------------------------
// fp32 fused GRU (kept for the action chain; INLINE_GI=0 path only)
// ---------------------------------------------------------------------------
template<int INLINE_GI>
__global__ __launch_bounds__(256)
void k_gru(const float* __restrict__ h_in, float* __restrict__ h_out,
           const float* __restrict__ gi,
           const float* __restrict__ Whh, const float* __restrict__ bhh)
{
    __shared__ float Xs[32][64];
    __shared__ float Ws[32][192];

    const int m0 = blockIdx.x * 64;
    const int j0 = blockIdx.y * 64;
    const int tid = threadIdx.x;
    const int tr = tid & 15, tc = tid >> 4;

    float acc[3][16];
    #pragma unroll
    for (int g = 0; g < 3; g++)
        #pragma unroll
        for (int i = 0; i < 16; i++) acc[g][i] = 0.f;

    for (int k0 = 0; k0 < H; k0 += 32) {
        #pragma unroll
        for (int i = 0; i < 2; i++) {
            int f = tid + 256*i;
            int m = f & 63, kk = (f >> 6) << 2;
            float4 v = *(const float4*)(h_in + (size_t)(m0+m)*H + k0 + kk);
            Xs[kk+0][m]=v.x; Xs[kk+1][m]=v.y; Xs[kk+2][m]=v.z; Xs[kk+3][m]=v.w;
        }
        #pragma unroll
        for (int i = 0; i < 6; i++) {
            int f = tid + 256*i;
            int c = f % 192, kk = (f / 192) << 2;
            int gate = c / 64, jc = j0 + (c & 63);
            float4 v = *(const float4*)(Whh + (size_t)(gate*H + jc)*H + k0 + kk);
            Ws[kk+0][c]=v.x; Ws[kk+1][c]=v.y; Ws[kk+2][c]=v.z; Ws[kk+3][c]=v.w;
        }
        __syncthreads();
        #pragma unroll
        for (int kk = 0; kk < 32; kk++) {
            float4 a = *(const float4*)&Xs[kk][tr*4];
            float av[4] = {a.x, a.y, a.z, a.w};
            #pragma unroll
            for (int g = 0; g < 3; g++) {
                float4 b = *(const float4*)&Ws[kk][g*64 + tc*4];
                float bv[4] = {b.x, b.y, b.z, b.w};
                #pragma unroll
                for (int ri = 0; ri < 4; ri++)
                    #pragma unroll
                    for (int ci = 0; ci < 4; ci++)
                        acc[g][ri*4+ci] = fmaf(av[ri], bv[ci], acc[g][ri*4+ci]);
            }
        }
        __syncthreads();
    }

    #pragma unroll
    for (int ri = 0; ri < 4; ri++) {
        int row = m0 + tr*4 + ri;
        #pragma unroll
        for (int ci = 0; ci < 4; ci++) {
            int col = j0 + tc*4 + ci;
            const float* gp = gi + (size_t)row*G3;
            float gr = gp[col], gz = gp[256+col], gn = gp[512+col];
            float hr = acc[0][ri*4+ci] + bhh[col];
            float hz = acc[1][ri*4+ci] + bhh[256+col];
            float hn = acc[2][ri*4+ci] + bhh[512+col];
            float r = sigmoid_(gr + hr);
            float z = sigmoid_(gz + hz);
            float n = tanh_(gn + r*hn);
            float ho = h_in[(size_t)row*H + col];
            h_out[(size_t)row*H + col] = (1.f - z)*n + z*ho;
        }
    }
}

// ---------------------------------------------------------------------------
// Generic fp32 C[M x N] = act( X[M x 256] @ W^T (+ bias | + Cin) )
// ---------------------------------------------------------------------------
template<int ACT, int ADD>
__global__ __launch_bounds__(256)
void k_gemm(const float* __restrict__ X, const float* __restrict__ W, int ldw,
            const float* __restrict__ bias, const float* __restrict__ Cin,
            float* __restrict__ C, int N)
{
    __shared__ float Xs[32][64];
    __shared__ float Ws[32][64];
    const int m0 = blockIdx.x*64, n0 = blockIdx.y*64;
    const int tid = threadIdx.x, tr = tid & 15, tc = tid >> 4;
    float acc[16];
    #pragma unroll
    for (int i = 0; i < 16; i++) acc[i] = 0.f;

    for (int k0 = 0; k0 < H; k0 += 32) {
        #pragma unroll
        for (int i = 0; i < 2; i++) {
            int f = tid + 256*i;
            int m = f & 63, kk = (f >> 6) << 2;
            float4 v = *(const float4*)(X + (size_t)(m0+m)*H + k0 + kk);
            Xs[kk+0][m]=v.x; Xs[kk+1][m]=v.y; Xs[kk+2][m]=v.z; Xs[kk+3][m]=v.w;
            const float* wp = W + (size_t)(n0+m)*ldw + k0 + kk;
            Ws[kk+0][m]=wp[0]; Ws[kk+1][m]=wp[1]; Ws[kk+2][m]=wp[2]; Ws[kk+3][m]=wp[3];
        }
        __syncthreads();
        #pragma unroll
        for (int kk = 0; kk < 32; kk++) {
            float4 a = *(const float4*)&Xs[kk][tr*4];
            float4 b = *(const float4*)&Ws[kk][tc*4];
            float av[4] = {a.x,a.y,a.z,a.w};
            float bv[4] = {b.x,b.y,b.z,b.w};
            #pragma unroll
            for (int ri = 0; ri < 4; ri++)
                #pragma unroll
                for (int ci = 0; ci < 4; ci++)
                    acc[ri*4+ci] = fmaf(av[ri], bv[ci], acc[ri*4+ci]);
        }
        __syncthreads();
    }
    #pragma unroll
    for (int ri = 0; ri < 4; ri++) {
        int row = m0 + tr*4 + ri;
        #pragma unroll
        for (int ci = 0; ci < 4; ci++) {
            int col = n0 + tc*4 + ci;
            float v = acc[ri*4+ci];
            if (ADD) v += Cin[(size_t)row*N + col];
            else     v += bias[col];
            if (ACT == 1) v = elu_(v);
            C[(size_t)row*N + col] = v;
        }
    }
}

// feat[ba][j] = max_e proc[ba*EE + e][j]
__global__ void k_pool(const float* __restrict__ proc, float* __restrict__ feat)
{
    int idx = blockIdx.x*256 + threadIdx.x;   // RA*H
    int ba = idx >> 8, j = idx & 255;
    const float* p = proc + (size_t)ba*EE*H + j;
    float m = p[0];
    #pragma unroll
    for (int e = 1; e < EE; e++) m = fmaxf(m, p[(size_t)e*H]);
    feat[idx] = m;
}

// out[row][v] = tanh(b_m2[v] + m1o[row] . W_m2[v]) * STEP
__global__ void k_m2(const float* __restrict__ X, const float* __restrict__ Wm2,
                     const float* __restrict__ bm2, float* __restrict__ out)
{
    int idx = blockIdx.x*256 + threadIdx.x;   // RA*NMV
    int row = idx >> 1, v = idx & 1;
    const float4* x = (const float4*)(X + (size_t)row*H);
    const float4* w = (const float4*)(Wm2 + (size_t)v*H);
    float s = bm2[v];
    #pragma unroll 4
    for (int i = 0; i < H/4; i++) {
        float4 a = x[i], b = w[i];
        s = fmaf(a.x, b.x, s); s = fmaf(a.y, b.y, s);
        s = fmaf(a.z, b.z, s); s = fmaf(a.w, b.w, s);
    }
    out[idx] = tanh_(s) * STEPSC;
}

extern "C" void kernel_launch(void* const* d_in, const int* in_sizes, int n_in,
                              void* d_out, int out_size, void* d_ws, size_t ws_size,
                              hipStream_t stream)
{
    const float* obs  = (const float*)d_in[0];
    const float* phys = (const float*)d_in[1];
    const float* goals= (const float*)d_in[2];
    const float* memp = (const float*)d_in[3];
    const float* mema = (const float*)d_in[4];
    const float* Wihp = (const float*)d_in[5];
    const float* Whhp = (const float*)d_in[6];
    const float* bihp = (const float*)d_in[7];
    const float* bhhp = (const float*)d_in[8];
    const float* Wfcp = (const float*)d_in[9];
    const float* bfcp = (const float*)d_in[10];
    const float* Wiha = (const float*)d_in[11];
    const float* Whha = (const float*)d_in[12];
    const float* biha = (const float*)d_in[13];
    const float* bhha = (const float*)d_in[14];
    const float* Wfca = (const float*)d_in[15];
    const float* bfca = (const float*)d_in[16];
    const float* Wm1  = (const float*)d_in[17];
    const float* bm1  = (const float*)d_in[18];
    const float* Wm2  = (const float*)d_in[19];
    const float* bm2  = (const float*)d_in[20];
    float* out = (float*)d_out;

    // --- workspace carve (16B aligned) ---
    char* base = (char*)d_ws;
    size_t off = 0;
    auto alloc = [&](size_t bytes) -> char* {
        char* p = base + off;
        off += (bytes + 255) & ~(size_t)255;
        return p;
    };
    unsigned short* whh_hi = (unsigned short*)alloc((size_t)G3*H*2);
    unsigned short* whh_lo = (unsigned short*)alloc((size_t)G3*H*2);
    unsigned short* wfc_hi = (unsigned short*)alloc((size_t)H*H*2);
    unsigned short* wfc_lo = (unsigned short*)alloc((size_t)H*H*2);
    unsigned short* hpA_hi = (unsigned short*)alloc((size_t)RP*H*2);
    unsigned short* hpA_lo = (unsigned short*)alloc((size_t)RP*H*2);
    unsigned short* hpB_hi = (unsigned short*)alloc((size_t)RP*H*2);
    unsigned short* hpB_lo = (unsigned short*)alloc((size_t)RP*H*2);
    float* gia_goal = (float*)alloc((size_t)RA*G3*4);
    float* gi_a     = (float*)alloc((size_t)RA*G3*4);
    float* ha0      = (float*)alloc((size_t)RA*H*4);
    float* ha1      = (float*)alloc((size_t)RA*H*4);
    float* proc     = (float*)alloc((size_t)RP*H*4);
    float* feat     = (float*)alloc((size_t)RA*H*4);
    float* proca    = (float*)alloc((size_t)RA*H*4);
    float* m1o      = (float*)alloc((size_t)RA*H*4);

    // --- pre-pass: split weights + initial physical memory; copy action mem ---
    k_split<<<(G3*H + 255)/256, 256, 0, stream>>>(Whhp, whh_hi, whh_lo, G3*H);
    k_split<<<(H*H + 255)/256, 256, 0, stream>>>(Wfcp, wfc_hi, wfc_lo, H*H);
    k_split<<<((size_t)RP*H + 255)/256, 256, 0, stream>>>(memp, hpA_hi, hpA_lo, RP*H);
    hipMemcpyAsync(ha0, mema, sizeof(float)*(size_t)RA*H, hipMemcpyDeviceToDevice, stream);
    k_gia_goal<<<RA*G3/256, 256, 0, stream>>>(goals, Wiha, biha, gia_goal);

    unsigned short *hi_i = hpA_hi, *lo_i = hpA_lo, *hi_o = hpB_hi, *lo_o = hpB_lo;
    float* hai = ha0; float* hao = ha1;
    for (int t = 0; t < TT; t++) {
        // physical chain (MFMA split-bf16)
        k_gru_mfma<<<dim3(RP/128, 8), 256, 0, stream>>>(hi_i, lo_i, hi_o, lo_o,
                                                        whh_hi, whh_lo,
                                                        obs, phys, Wihp, bihp, bhhp);
        k_fc_mfma<<<dim3(RP/128, 4), 256, 0, stream>>>(hi_o, lo_o, wfc_hi, wfc_lo, bfcp, proc);
        k_pool<<<RA*H/256, 256, 0, stream>>>(proc, feat);
        // action chain (fp32)
        k_gemm<0,1><<<dim3(RA/64, G3/64), 256, 0, stream>>>(feat, Wiha, 259, nullptr, gia_goal, gi_a, G3);
        k_gru<0><<<dim3(RA/64, 4), 256, 0, stream>>>(hai, hao, gi_a, Whha, bhha);
        k_gemm<1,0><<<dim3(RA/64, H/64), 256, 0, stream>>>(hao, Wfca, H, bfca, nullptr, proca, H);
        k_gemm<1,0><<<dim3(RA/64, H/64), 256, 0, stream>>>(proca, Wm1, H, bm1, nullptr, m1o, H);
        k_m2<<<RA*NMV/256, 256, 0, stream>>>(m1o, Wm2, bm2, out + (size_t)t*RA*NMV);

        unsigned short* ts;
        ts = hi_i; hi_i = hi_o; hi_o = ts;
        ts = lo_i; lo_i = lo_o; lo_o = ts;
        float* tf = hai; hai = hao; hao = tf;
    }
}

// Round 3
// 1653.674 us; speedup vs baseline: 2.1076x; 1.4753x over previous
//
#include <hip/hip_runtime.h>
#include <math.h>

#define H 256
#define G3 768        // 3*H
#define BB 512
#define AA 4
#define EE 10
#define RP (BB*AA*EE) // 20480 physical rows
#define RA (BB*AA)    // 2048 action rows
#define TT 10
#define NMV 2
#define STEPSC 0.05f
#define LDW 264       // LDS row stride in shorts (33*8: breaks bank aliasing, keeps 16B align)

typedef __attribute__((ext_vector_type(8))) short short8;
typedef __attribute__((ext_vector_type(4))) float f32x4;
typedef unsigned short ushort_t;

__device__ __forceinline__ float sigmoid_(float x){ return 1.f/(1.f + __expf(-x)); }
__device__ __forceinline__ float tanh_(float x){
    float ax = fabsf(x);
    float e  = __expf(-2.f*ax);
    float t  = (1.f - e)/(1.f + e);
    return copysignf(t, x);
}
__device__ __forceinline__ float elu_(float x){ return x > 0.f ? x : (__expf(x) - 1.f); }

__device__ __forceinline__ ushort_t f2bf(float x){
    union { float f; unsigned int u; } v; v.f = x;
    unsigned int r = v.u + 0x7fffu + ((v.u >> 16) & 1u);
    return (ushort_t)(r >> 16);
}
__device__ __forceinline__ float bf2f(ushort_t b){
    union { unsigned int u; float f; } v; v.u = ((unsigned int)b) << 16; return v.f;
}

// ---------------------------------------------------------------------------
// split fp32 -> (hi, lo) bf16 pair
// ---------------------------------------------------------------------------
__global__ void k_split(const float* __restrict__ src,
                        ushort_t* __restrict__ hi, ushort_t* __restrict__ lo, int n)
{
    int i = blockIdx.x*256 + threadIdx.x;
    if (i < n) {
        float x = src[i];
        ushort_t h = f2bf(x);
        hi[i] = h;
        lo[i] = f2bf(x - bf2f(h));
    }
}

// split with source leading-dim 259, keep first 256 cols (W_ih_a feat part)
__global__ void k_split_ld(const float* __restrict__ src,
                           ushort_t* __restrict__ hi, ushort_t* __restrict__ lo, int n)
{
    int i = blockIdx.x*256 + threadIdx.x;
    if (i < n) {
        int r = i >> 8, c = i & 255;
        float x = src[(size_t)r*259 + c];
        ushort_t h = f2bf(x);
        hi[i] = h;
        lo[i] = f2bf(x - bf2f(h));
    }
}

// gia_goal[ra][k] = b_ih_a[k] + sum_{j<3} goals[ra][j]*W_ih_a[k][256+j]
__global__ void k_gia_goal(const float* __restrict__ goals,
                           const float* __restrict__ Wiha,
                           const float* __restrict__ biha,
                           float* __restrict__ out)
{
    int idx = blockIdx.x*256 + threadIdx.x;
    int ra = idx / G3, k = idx % G3;
    float g0 = goals[ra*3+0], g1 = goals[ra*3+1], g2 = goals[ra*3+2];
    const float* w = Wiha + (size_t)k*259 + 256;
    out[idx] = biha[k] + g0*w[0] + g1*w[1] + g2*w[2];
}

// ---------------------------------------------------------------------------
// Fused MFMA GRU step, LDS-resident weights + full-A register preload.
// Block: 256 thr = 4 waves; 128-row tile; 16-col slice (48 weight rows in LDS).
// Wave tile: 32 rows x 16 cols x 3 gates. K-loop is pure LDS + MFMA.
// ---------------------------------------------------------------------------
template<int INLINE_GI>
__global__ __launch_bounds__(256, 2)
void k_gru2(const ushort_t* __restrict__ h_hi, const ushort_t* __restrict__ h_lo,
            ushort_t* __restrict__ o_hi, ushort_t* __restrict__ o_lo,
            const ushort_t* __restrict__ w_hi, const ushort_t* __restrict__ w_lo,
            const float* __restrict__ gi,
            const float* __restrict__ obs, const float* __restrict__ phys,
            const float* __restrict__ Wih, const float* __restrict__ bih,
            const float* __restrict__ bhh)
{
    __shared__ ushort_t Bhi[48*LDW];
    __shared__ ushort_t Blo[48*LDW];
    __shared__ float WihS[48*5];
    __shared__ float bihS[48];
    __shared__ float bhhS[48];

    const int tid = threadIdx.x;
    const int j0 = blockIdx.y * 16;

    // --- stage weight slice: 48 rows (3 gates x 16 cols) x 256 k ---
    for (int c = tid; c < 48*32; c += 256) {
        int r = c >> 5, kc8 = c & 31;
        int gate = r >> 4, colrel = r & 15;
        size_t gsrc = (size_t)(gate*H + j0 + colrel)*H + kc8*8;
        *(short8*)&Bhi[r*LDW + kc8*8] = *(const short8*)(w_hi + gsrc);
        *(short8*)&Blo[r*LDW + kc8*8] = *(const short8*)(w_lo + gsrc);
    }
    if (INLINE_GI) {
        for (int c = tid; c < 240; c += 256) {
            int r = c/5, j = c%5;
            WihS[c] = Wih[(size_t)((r>>4)*H + j0 + (r&15))*5 + j];
        }
    }
    if (tid < 48) {
        int r = tid;
        int gcol = (r>>4)*H + j0 + (r&15);
        if (INLINE_GI) bihS[r] = bih[gcol];
        bhhS[r] = bhh[gcol];
    }

    // --- full A preload (32 rows per wave, hi+lo, all K) ---
    const int wv = tid >> 6, lane = tid & 63;
    const int quad = lane >> 4, l16 = lane & 15;
    const int m0 = blockIdx.x*128 + wv*32;
    const size_t a0 = (size_t)(m0 + l16)*H + quad*8;
    const size_t a1 = a0 + (size_t)16*H;
    short8 Ah[2][8], Al[2][8];
    #pragma unroll
    for (int kc = 0; kc < 8; kc++) {
        Ah[0][kc] = *(const short8*)(h_hi + a0 + kc*32);
        Al[0][kc] = *(const short8*)(h_lo + a0 + kc*32);
        Ah[1][kc] = *(const short8*)(h_hi + a1 + kc*32);
        Al[1][kc] = *(const short8*)(h_lo + a1 + kc*32);
    }

    __syncthreads();

    f32x4 acc[3][2];
    #pragma unroll
    for (int g = 0; g < 3; g++)
        #pragma unroll
        for (int mi = 0; mi < 2; mi++)
            acc[g][mi] = (f32x4){0.f,0.f,0.f,0.f};

    #pragma unroll
    for (int kc = 0; kc < 8; kc++) {
        #pragma unroll
        for (int g = 0; g < 3; g++) {
            int br = g*16 + l16;
            short8 bhv = *(const short8*)&Bhi[br*LDW + kc*32 + quad*8];
            short8 blv = *(const short8*)&Blo[br*LDW + kc*32 + quad*8];
            acc[g][0] = __builtin_amdgcn_mfma_f32_16x16x32_bf16(Ah[0][kc], bhv, acc[g][0], 0,0,0);
            acc[g][0] = __builtin_amdgcn_mfma_f32_16x16x32_bf16(Al[0][kc], bhv, acc[g][0], 0,0,0);
            acc[g][0] = __builtin_amdgcn_mfma_f32_16x16x32_bf16(Ah[0][kc], blv, acc[g][0], 0,0,0);
            acc[g][1] = __builtin_amdgcn_mfma_f32_16x16x32_bf16(Ah[1][kc], bhv, acc[g][1], 0,0,0);
            acc[g][1] = __builtin_amdgcn_mfma_f32_16x16x32_bf16(Al[1][kc], bhv, acc[g][1], 0,0,0);
            acc[g][1] = __builtin_amdgcn_mfma_f32_16x16x32_bf16(Ah[1][kc], blv, acc[g][1], 0,0,0);
        }
    }

    // --- epilogue ---
    const int col = j0 + l16;
    #pragma unroll
    for (int mi = 0; mi < 2; mi++) {
        #pragma unroll
        for (int r = 0; r < 4; r++) {
            int row = m0 + mi*16 + quad*4 + r;
            float gr, gz, gn;
            if (INLINE_GI) {
                float x0 = obs[(size_t)row*2+0];
                float x1 = obs[(size_t)row*2+1];
                int b = row / (AA*EE);
                int e = row % EE;
                const float* pp = phys + (size_t)(b*EE + e)*3;
                float x2 = pp[0], x3 = pp[1], x4 = pp[2];
                gr = bihS[l16]; gz = bihS[16+l16]; gn = bihS[32+l16];
                const float* wr = &WihS[l16*5];
                const float* wz = &WihS[(16+l16)*5];
                const float* wn = &WihS[(32+l16)*5];
                gr = fmaf(x0,wr[0],gr); gr = fmaf(x1,wr[1],gr); gr = fmaf(x2,wr[2],gr);
                gr = fmaf(x3,wr[3],gr); gr = fmaf(x4,wr[4],gr);
                gz = fmaf(x0,wz[0],gz); gz = fmaf(x1,wz[1],gz); gz = fmaf(x2,wz[2],gz);
                gz = fmaf(x3,wz[3],gz); gz = fmaf(x4,wz[4],gz);
                gn = fmaf(x0,wn[0],gn); gn = fmaf(x1,wn[1],gn); gn = fmaf(x2,wn[2],gn);
                gn = fmaf(x3,wn[3],gn); gn = fmaf(x4,wn[4],gn);
            } else {
                const float* gp = gi + (size_t)row*G3;
                gr = gp[col]; gz = gp[256+col]; gn = gp[512+col];
            }
            float hr = acc[0][mi][r] + bhhS[l16];
            float hz = acc[1][mi][r] + bhhS[16+l16];
            float hn = acc[2][mi][r] + bhhS[32+l16];
            float rg = sigmoid_(gr + hr);
            float z  = sigmoid_(gz + hz);
            float n  = tanh_(gn + rg*hn);
            size_t idx = (size_t)row*H + col;
            float hprev = bf2f(h_hi[idx]) + bf2f(h_lo[idx]);
            float h = (1.f - z)*n + z*hprev;
            ushort_t hb = f2bf(h);
            o_hi[idx] = hb;
            o_lo[idx] = f2bf(h - bf2f(hb));
        }
    }
}

// ---------------------------------------------------------------------------
// MFMA GEMM, LDS-resident weights + A register preload. 32-col slice.
// MODE 0: out = split(elu(acc + bias)) -> o_hi/o_lo
// MODE 1: out_f32 = acc + Cin
// ---------------------------------------------------------------------------
template<int MODE>
__global__ __launch_bounds__(256, 2)
void k_fc2(const ushort_t* __restrict__ h_hi, const ushort_t* __restrict__ h_lo,
           const ushort_t* __restrict__ w_hi, const ushort_t* __restrict__ w_lo,
           const float* __restrict__ bias, const float* __restrict__ Cin, int N,
           ushort_t* __restrict__ o_hi, ushort_t* __restrict__ o_lo,
           float* __restrict__ o_f32)
{
    __shared__ ushort_t Bhi[32*LDW];
    __shared__ ushort_t Blo[32*LDW];

    const int tid = threadIdx.x;
    const int j0 = blockIdx.y * 32;

    for (int c = tid; c < 32*32; c += 256) {
        int r = c >> 5, kc8 = c & 31;
        size_t gsrc = (size_t)(j0 + r)*H + kc8*8;
        *(short8*)&Bhi[r*LDW + kc8*8] = *(const short8*)(w_hi + gsrc);
        *(short8*)&Blo[r*LDW + kc8*8] = *(const short8*)(w_lo + gsrc);
    }

    const int wv = tid >> 6, lane = tid & 63;
    const int quad = lane >> 4, l16 = lane & 15;
    const int m0 = blockIdx.x*128 + wv*32;
    const size_t a0 = (size_t)(m0 + l16)*H + quad*8;
    const size_t a1 = a0 + (size_t)16*H;
    short8 Ah[2][8], Al[2][8];
    #pragma unroll
    for (int kc = 0; kc < 8; kc++) {
        Ah[0][kc] = *(const short8*)(h_hi + a0 + kc*32);
        Al[0][kc] = *(const short8*)(h_lo + a0 + kc*32);
        Ah[1][kc] = *(const short8*)(h_hi + a1 + kc*32);
        Al[1][kc] = *(const short8*)(h_lo + a1 + kc*32);
    }

    __syncthreads();

    f32x4 acc[2][2];   // [mi][ni]
    #pragma unroll
    for (int mi = 0; mi < 2; mi++)
        #pragma unroll
        for (int ni = 0; ni < 2; ni++)
            acc[mi][ni] = (f32x4){0.f,0.f,0.f,0.f};

    #pragma unroll
    for (int kc = 0; kc < 8; kc++) {
        #pragma unroll
        for (int ni = 0; ni < 2; ni++) {
            int br = ni*16 + l16;
            short8 bhv = *(const short8*)&Bhi[br*LDW + kc*32 + quad*8];
            short8 blv = *(const short8*)&Blo[br*LDW + kc*32 + quad*8];
            acc[0][ni] = __builtin_amdgcn_mfma_f32_16x16x32_bf16(Ah[0][kc], bhv, acc[0][ni], 0,0,0);
            acc[0][ni] = __builtin_amdgcn_mfma_f32_16x16x32_bf16(Al[0][kc], bhv, acc[0][ni], 0,0,0);
            acc[0][ni] = __builtin_amdgcn_mfma_f32_16x16x32_bf16(Ah[0][kc], blv, acc[0][ni], 0,0,0);
            acc[1][ni] = __builtin_amdgcn_mfma_f32_16x16x32_bf16(Ah[1][kc], bhv, acc[1][ni], 0,0,0);
            acc[1][ni] = __builtin_amdgcn_mfma_f32_16x16x32_bf16(Al[1][kc], bhv, acc[1][ni], 0,0,0);
            acc[1][ni] = __builtin_amdgcn_mfma_f32_16x16x32_bf16(Ah[1][kc], blv, acc[1][ni], 0,0,0);
        }
    }

    #pragma unroll
    for (int mi = 0; mi < 2; mi++) {
        #pragma unroll
        for (int r = 0; r < 4; r++) {
            int row = m0 + mi*16 + quad*4 + r;
            #pragma unroll
            for (int ni = 0; ni < 2; ni++) {
                int colg = j0 + ni*16 + l16;
                size_t idx = (size_t)row*N + colg;
                float v = acc[mi][ni][r];
                if (MODE == 0) {
                    v = elu_(v + bias[colg]);
                    ushort_t hb = f2bf(v);
                    o_hi[idx] = hb;
                    o_lo[idx] = f2bf(v - bf2f(hb));
                } else {
                    o_f32[idx] = v + Cin[idx];
                }
            }
        }
    }
}

// feat[ba][j] = max_e (proc_hi+proc_lo), output split
__global__ void k_pool2(const ushort_t* __restrict__ p_hi, const ushort_t* __restrict__ p_lo,
                        ushort_t* __restrict__ f_hi, ushort_t* __restrict__ f_lo)
{
    int idx = blockIdx.x*256 + threadIdx.x;   // RA*H
    int ba = idx >> 8, j = idx & 255;
    size_t base = (size_t)ba*EE*H + j;
    float m = bf2f(p_hi[base]) + bf2f(p_lo[base]);
    #pragma unroll
    for (int e = 1; e < EE; e++) {
        float v = bf2f(p_hi[base + (size_t)e*H]) + bf2f(p_lo[base + (size_t)e*H]);
        m = fmaxf(m, v);
    }
    ushort_t hb = f2bf(m);
    f_hi[idx] = hb;
    f_lo[idx] = f2bf(m - bf2f(hb));
}

// out[row][v] = tanh(b_m2[v] + (m1_hi+m1_lo)[row] . W_m2[v]) * STEP
__global__ void k_m2(const ushort_t* __restrict__ xh, const ushort_t* __restrict__ xl,
                     const float* __restrict__ Wm2, const float* __restrict__ bm2,
                     float* __restrict__ out)
{
    int idx = blockIdx.x*256 + threadIdx.x;   // RA*NMV
    int row = idx >> 1, v = idx & 1;
    const short8* ph = (const short8*)(xh + (size_t)row*H);
    const short8* pl = (const short8*)(xl + (size_t)row*H);
    const float* w = Wm2 + (size_t)v*H;
    float s = bm2[v];
    #pragma unroll 4
    for (int i = 0; i < H/8; i++) {
        short8 a = ph[i], b = pl[i];
        #pragma unroll
        for (int j = 0; j < 8; j++) {
            float x = bf2f((ushort_t)a[j]) + bf2f((ushort_t)b[j]);
            s = fmaf(x, w[i*8+j], s);
        }
    }
    out[idx] = tanh_(s) * STEPSC;
}

extern "C" void kernel_launch(void* const* d_in, const int* in_sizes, int n_in,
                              void* d_out, int out_size, void* d_ws, size_t ws_size,
                              hipStream_t stream)
{
    const float* obs  = (const float*)d_in[0];
    const float* phys = (const float*)d_in[1];
    const float* goals= (const float*)d_in[2];
    const float* memp = (const float*)d_in[3];
    const float* mema = (const float*)d_in[4];
    const float* Wihp = (const float*)d_in[5];
    const float* Whhp = (const float*)d_in[6];
    const float* bihp = (const float*)d_in[7];
    const float* bhhp = (const float*)d_in[8];
    const float* Wfcp = (const float*)d_in[9];
    const float* bfcp = (const float*)d_in[10];
    const float* Wiha = (const float*)d_in[11];
    const float* Whha = (const float*)d_in[12];
    const float* biha = (const float*)d_in[13];
    const float* bhha = (const float*)d_in[14];
    const float* Wfca = (const float*)d_in[15];
    const float* bfca = (const float*)d_in[16];
    const float* Wm1  = (const float*)d_in[17];
    const float* bm1  = (const float*)d_in[18];
    const float* Wm2  = (const float*)d_in[19];
    const float* bm2  = (const float*)d_in[20];
    float* out = (float*)d_out;

    char* base = (char*)d_ws;
    size_t off = 0;
    auto alloc = [&](size_t bytes) -> char* {
        char* p = base + off;
        off += (bytes + 255) & ~(size_t)255;
        return p;
    };
    ushort_t* whh_hi  = (ushort_t*)alloc((size_t)G3*H*2);
    ushort_t* whh_lo  = (ushort_t*)alloc((size_t)G3*H*2);
    ushort_t* wfc_hi  = (ushort_t*)alloc((size_t)H*H*2);
    ushort_t* wfc_lo  = (ushort_t*)alloc((size_t)H*H*2);
    ushort_t* whha_hi = (ushort_t*)alloc((size_t)G3*H*2);
    ushort_t* whha_lo = (ushort_t*)alloc((size_t)G3*H*2);
    ushort_t* wiha_hi = (ushort_t*)alloc((size_t)G3*H*2);
    ushort_t* wiha_lo = (ushort_t*)alloc((size_t)G3*H*2);
    ushort_t* wfca_hi = (ushort_t*)alloc((size_t)H*H*2);
    ushort_t* wfca_lo = (ushort_t*)alloc((size_t)H*H*2);
    ushort_t* wm1_hi  = (ushort_t*)alloc((size_t)H*H*2);
    ushort_t* wm1_lo  = (ushort_t*)alloc((size_t)H*H*2);
    ushort_t* hpA_hi  = (ushort_t*)alloc((size_t)RP*H*2);
    ushort_t* hpA_lo  = (ushort_t*)alloc((size_t)RP*H*2);
    ushort_t* hpB_hi  = (ushort_t*)alloc((size_t)RP*H*2);
    ushort_t* hpB_lo  = (ushort_t*)alloc((size_t)RP*H*2);
    ushort_t* haA_hi  = (ushort_t*)alloc((size_t)RA*H*2);
    ushort_t* haA_lo  = (ushort_t*)alloc((size_t)RA*H*2);
    ushort_t* haB_hi  = (ushort_t*)alloc((size_t)RA*H*2);
    ushort_t* haB_lo  = (ushort_t*)alloc((size_t)RA*H*2);
    ushort_t* proc_hi = (ushort_t*)alloc((size_t)RP*H*2);
    ushort_t* proc_lo = (ushort_t*)alloc((size_t)RP*H*2);
    ushort_t* feat_hi = (ushort_t*)alloc((size_t)RA*H*2);
    ushort_t* feat_lo = (ushort_t*)alloc((size_t)RA*H*2);
    float* gia_goal   = (float*)alloc((size_t)RA*G3*4);
    float* gi_a       = (float*)alloc((size_t)RA*G3*4);
    // transient action tensors alias the (dead-at-that-point) proc region
    ushort_t* proca_hi = proc_hi;
    ushort_t* proca_lo = proc_hi + (size_t)RA*H;
    ushort_t* m1o_hi   = proc_hi + (size_t)2*RA*H;
    ushort_t* m1o_lo   = proc_hi + (size_t)3*RA*H;

    // --- pre-pass: split weights and initial states ---
    k_split   <<<(G3*H+255)/256, 256, 0, stream>>>(Whhp, whh_hi, whh_lo, G3*H);
    k_split   <<<(H*H+255)/256, 256, 0, stream>>>(Wfcp, wfc_hi, wfc_lo, H*H);
    k_split   <<<(G3*H+255)/256, 256, 0, stream>>>(Whha, whha_hi, whha_lo, G3*H);
    k_split_ld<<<(G3*H+255)/256, 256, 0, stream>>>(Wiha, wiha_hi, wiha_lo, G3*H);
    k_split   <<<(H*H+255)/256, 256, 0, stream>>>(Wfca, wfca_hi, wfca_lo, H*H);
    k_split   <<<(H*H+255)/256, 256, 0, stream>>>(Wm1, wm1_hi, wm1_lo, H*H);
    k_split   <<<((size_t)RP*H+255)/256, 256, 0, stream>>>(memp, hpA_hi, hpA_lo, RP*H);
    k_split   <<<((size_t)RA*H+255)/256, 256, 0, stream>>>(mema, haA_hi, haA_lo, RA*H);
    k_gia_goal<<<RA*G3/256, 256, 0, stream>>>(goals, Wiha, biha, gia_goal);

    ushort_t *pi_h = hpA_hi, *pi_l = hpA_lo, *po_h = hpB_hi, *po_l = hpB_lo;
    ushort_t *ai_h = haA_hi, *ai_l = haA_lo, *ao_h = haB_hi, *ao_l = haB_lo;
    for (int t = 0; t < TT; t++) {
        // physical chain
        k_gru2<1><<<dim3(RP/128, 16), 256, 0, stream>>>(pi_h, pi_l, po_h, po_l,
                                                        whh_hi, whh_lo, nullptr,
                                                        obs, phys, Wihp, bihp, bhhp);
        k_fc2<0><<<dim3(RP/128, 8), 256, 0, stream>>>(po_h, po_l, wfc_hi, wfc_lo,
                                                      bfcp, nullptr, H, proc_hi, proc_lo, nullptr);
        k_pool2<<<RA*H/256, 256, 0, stream>>>(proc_hi, proc_lo, feat_hi, feat_lo);
        // action chain
        k_fc2<1><<<dim3(RA/128, G3/32), 256, 0, stream>>>(feat_hi, feat_lo, wiha_hi, wiha_lo,
                                                          nullptr, gia_goal, G3, nullptr, nullptr, gi_a);
        k_gru2<0><<<dim3(RA/128, 16), 256, 0, stream>>>(ai_h, ai_l, ao_h, ao_l,
                                                        whha_hi, whha_lo, gi_a,
                                                        nullptr, nullptr, nullptr, nullptr, bhha);
        k_fc2<0><<<dim3(RA/128, 8), 256, 0, stream>>>(ao_h, ao_l, wfca_hi, wfca_lo,
                                                      bfca, nullptr, H, proca_hi, proca_lo, nullptr);
        k_fc2<0><<<dim3(RA/128, 8), 256, 0, stream>>>(proca_hi, proca_lo, wm1_hi, wm1_lo,
                                                      bm1, nullptr, H, m1o_hi, m1o_lo, nullptr);
        k_m2<<<RA*NMV/256, 256, 0, stream>>>(m1o_hi, m1o_lo, Wm2, bm2, out + (size_t)t*RA*NMV);

        ushort_t* ts;
        ts = pi_h; pi_h = po_h; po_h = ts;
        ts = pi_l; pi_l = po_l; po_l = ts;
        ts = ai_h; ai_h = ao_h; ao_h = ts;
        ts = ai_l; ai_l = ao_l; ao_l = ts;
    }
}